// Round 16
// baseline (97.261 us; speedup 1.0000x reference)
//
#include <hip/hip_runtime.h>

#define N_NODES 4096
#define KNN 9
#define CAPS 128                // topk survivor capacity per row (2 per lane)
#define CAPE 32                 // max edges per node in strided elist
#define THRESH 0.99f
#define GEMMB 1024              // blocks in the topk half of s0

__device__ __forceinline__ bool vi_greater(float av, int aj, float bv, int bj) {
  // order: larger value first; ties -> smaller index first (matches lax.top_k)
  return (av > bv) || (av == bv && aj < bj);
}

// ---- S0: heterogeneous dispatch. Blocks [0,GEMMB): topk -> idx (long pole,
// launched first). Blocks [GEMMB,2*GEMMB): P1 = x W10 + b10, x->out copy,
// zero cur. Fully independent halves, no cross-group sync.
__global__ __launch_bounds__(256) void s0_kernel(const float* __restrict__ x,
                                                 const float* __restrict__ adj,
                                                 const float* __restrict__ W10,
                                                 const float* __restrict__ b10,
                                                 float* __restrict__ P,
                                                 float* __restrict__ xcopy,
                                                 int* __restrict__ cur,
                                                 int* __restrict__ idx) {
  __shared__ float sf[1024];          // topk: 4 wave regions x 128 ; gemm: ylds
  __shared__ int   si[512];           // topk: 4 wave regions x 128
  const int tid = threadIdx.x;

  if (blockIdx.x < GEMMB) {
    // ---------- topk half ----------
    const int lane = tid & 63, wv = tid >> 6;
    const int row = blockIdx.x * 4 + wv;
    const float4* r4 = reinterpret_cast<const float4*>(adj + (size_t)row * N_NODES);
    float* wval = sf + wv * CAPS;
    int*   widx = si + wv * CAPS;

    // (1) prefetch the whole row slice: one latency wall, 16 loads in flight
    float4 f4[16];
#pragma unroll
    for (int t = 0; t < 16; ++t) f4[t] = r4[t * 64 + lane];

    // (2) per-lane survivor count — pure VALU, no cross-lane ops
    int lc = 0;
#pragma unroll
    for (int t = 0; t < 16; ++t) {
      lc += (f4[t].x > THRESH);
      lc += (f4[t].y > THRESH);
      lc += (f4[t].z > THRESH);
      lc += (f4[t].w > THRESH);
    }
    // (3) wave exclusive prefix scan (6 shfl steps)
    int off = lc;
#pragma unroll
    for (int d = 1; d < 64; d <<= 1) {
      int o = __shfl_up(off, d);
      if (lane >= d) off += o;
    }
    const int n = __shfl(off, 63);   // total survivors in this row
    int p = off - lc;                // this lane's write base
    // (4) second register pass: compacted LDS writes, no ballots
#pragma unroll
    for (int t = 0; t < 16; ++t) {
      float vv[4] = {f4[t].x, f4[t].y, f4[t].z, f4[t].w};
      int cb = (t * 64 + lane) * 4;
#pragma unroll
      for (int q = 0; q < 4; ++q) {
        if (vv[q] > THRESH && p < CAPS) { wval[p] = vv[q]; widx[p] = cb + q; ++p; }
      }
    }
    // per-wave LDS region written and read by the same wave: program order.

    if (n >= 9 && n <= CAPS) {
      // RANK-BASED top-8: candidate rank = #{valid survivors greater}.
      // Broadcast scan over LDS — parallel, no shfl chains. Ranks 0..7 are
      // the top-8 (order-independent of LDS layout). Slot 8 = center node.
      bool val0 = lane < n, val1 = lane + 64 < n;
      float v0 = 0.f, v1 = 0.f; int c0 = -1, c1 = -1;
      if (val0) { v0 = wval[lane];      c0 = widx[lane]; }
      if (val1) { v1 = wval[lane + 64]; c1 = widx[lane + 64]; }
      if (c0 == row) val0 = false;      // reference zeroes the diagonal
      if (c1 == row) val1 = false;
      int r0 = 0, r1 = 0;
      if (n <= 64) {
        for (int s = 0; s < n; ++s) {
          float vs = wval[s]; int cs = widx[s];
          if (cs != row && vi_greater(vs, cs, v0, c0)) ++r0;
        }
      } else {
        for (int s = 0; s < n; ++s) {
          float vs = wval[s]; int cs = widx[s];
          bool d = (cs != row);
          if (d && vi_greater(vs, cs, v0, c0)) ++r0;
          if (d && vi_greater(vs, cs, v1, c1)) ++r1;
        }
      }
      if (val0 && r0 < 8) idx[row * KNN + r0] = c0;
      if (val1 && r1 < 8) idx[row * KNN + r1] = c1;
      if (lane == 0)      idx[row * KNN + 8] = row;
    } else {
      // exact fallback: full-row per-lane sorted top-9 + 9 extraction rounds
      const float* r = adj + (size_t)row * N_NODES;
      float v[9]; int ji[9];
#pragma unroll
      for (int t = 0; t < 9; ++t) { v[t] = -3.0e38f; ji[t] = 0x7fffffff; }
      for (int t = 0; t < 64; ++t) {
        int cc = t * 64 + lane;
        float val = (cc == row) ? 0.0f : r[cc];
        if (vi_greater(val, cc, v[8], ji[8])) {
          v[8] = val; ji[8] = cc;
#pragma unroll
          for (int s = 8; s > 0; --s) {
            if (vi_greater(v[s], ji[s], v[s-1], ji[s-1])) {
              float tv = v[s]; v[s] = v[s-1]; v[s-1] = tv;
              int tj = ji[s]; ji[s] = ji[s-1]; ji[s-1] = tj;
            }
          }
        }
      }
      int o0=0,o1=0,o2=0,o3=0,o4=0,o5=0,o6=0,o7=0,o8=0;
      bool has_center = false;
#pragma unroll
      for (int rnd = 0; rnd < 9; ++rnd) {
        float mv = v[0]; int mj = ji[0];
#pragma unroll
        for (int d = 1; d < 64; d <<= 1) {
          float ov = __shfl_xor(mv, d);
          int   oj = __shfl_xor(mj, d);
          if (vi_greater(ov, oj, mv, mj)) { mv = ov; mj = oj; }
        }
        switch (rnd) {   // static targets (avoid dynamic reg-array indexing)
          case 0: o0 = mj; break; case 1: o1 = mj; break;
          case 2: o2 = mj; break; case 3: o3 = mj; break;
          case 4: o4 = mj; break; case 5: o5 = mj; break;
          case 6: o6 = mj; break; case 7: o7 = mj; break;
          default: o8 = mj; break;
        }
        has_center = has_center || (mj == row);
        if (ji[0] == mj) {
#pragma unroll
          for (int s = 0; s < 8; ++s) { v[s] = v[s+1]; ji[s] = ji[s+1]; }
          v[8] = -3.0e38f; ji[8] = 0x7fffffff;
        }
      }
      if (!has_center) o8 = row;
      if (lane == 0) {
        int* ip = idx + row * KNN;
        ip[0]=o0; ip[1]=o1; ip[2]=o2; ip[3]=o3; ip[4]=o4;
        ip[5]=o5; ip[6]=o6; ip[7]=o7; ip[8]=o8;
      }
    }
  } else {
    // ---------- dense GEMM half ----------
    int bb0 = blockIdx.x - GEMMB;
    int gid = bb0 * 256 + tid;
    if (gid < N_NODES) cur[gid] = 0;
    int m0 = bb0 * 4;
    {
      float4 y4 = reinterpret_cast<const float4*>(x + (size_t)m0 * 256)[tid];
      reinterpret_cast<float4*>(sf)[tid] = y4;
      reinterpret_cast<float4*>(xcopy + (size_t)m0 * 256)[tid] = y4;
    }
    __syncthreads();
    const int f  = tid & 127;
    const int rb = (tid >> 7) * 2;
    float a0 = 0.f, a1 = 0.f;
    for (int k = 0; k < 256; k += 4) {
      float w0 = W10[(k + 0) * 128 + f];
      float w1 = W10[(k + 1) * 128 + f];
      float w2 = W10[(k + 2) * 128 + f];
      float w3 = W10[(k + 3) * 128 + f];
      float4 y0 = *reinterpret_cast<const float4*>(&sf[(rb + 0) * 256 + k]);
      float4 y1 = *reinterpret_cast<const float4*>(&sf[(rb + 1) * 256 + k]);
      a0 = fmaf(y0.x, w0, fmaf(y0.y, w1, fmaf(y0.z, w2, fmaf(y0.w, w3, a0))));
      a1 = fmaf(y1.x, w0, fmaf(y1.y, w1, fmaf(y1.z, w2, fmaf(y1.w, w3, a1))));
    }
    float bb = b10[f];
    P[(size_t)(m0 + rb + 0) * 128 + f] = a0 + bb;
    P[(size_t)(m0 + rb + 1) * 128 + f] = a1 + bb;
  }
}

// D2: build strided inverse list (cur zeroed in s0's gemm half; == DV after).
__global__ void build_elist(const int* __restrict__ idx, int* __restrict__ cur,
                            int* __restrict__ elist) {
  int t = blockIdx.x * blockDim.x + threadIdx.x;
  if (t >= N_NODES * KNN) return;
  int node = idx[t];
  int p = atomicAdd(&cur[node], 1);
  if (p < CAPE) elist[node * CAPE + p] = t / KNN;
}

// Stage A: Z[e,f] = (1/9) * sum_j DV[idx[e][j]]^-1/2 * Y[idx[e][j], f]
template<int F>
__global__ __launch_bounds__(F) void edge_gather(const float* __restrict__ Y,
                                                 const int* __restrict__ idx,
                                                 const int* __restrict__ DV,
                                                 float* __restrict__ Z) {
  __shared__ int er[KNN];
  __shared__ float ew[KNN];
  int e = blockIdx.x;
  if (threadIdx.x < KNN) {
    int r = idx[e * KNN + threadIdx.x];
    er[threadIdx.x] = r;
    ew[threadIdx.x] = rsqrtf((float)DV[r]);
  }
  __syncthreads();
  int f = threadIdx.x;
  float acc = 0.f;
#pragma unroll
  for (int j = 0; j < KNN; ++j)
    acc = fmaf(ew[j], Y[(size_t)er[j] * F + f], acc);
  Z[(size_t)e * F + f] = acc * (1.0f / 9.0f);
}

// Branch-free node accumulate: 16 unconditional masked loads. elist is NOT
// initialized — entries clamped in-bounds with &(N-1); cndmask zeroes poison.
template<int KD>
__device__ __forceinline__ float node_acc(const float* __restrict__ Z,
                                          const int* __restrict__ elist,
                                          int i, int f, int cnt) {
  const int4* el4 = reinterpret_cast<const int4*>(elist + i * CAPE);
  int4 ea = el4[0], eb = el4[1], ec = el4[2], ed = el4[3];
  int e1[16] = {ea.x, ea.y, ea.z, ea.w, eb.x, eb.y, eb.z, eb.w,
                ec.x, ec.y, ec.z, ec.w, ed.x, ed.y, ed.z, ed.w};
  float acc = 0.f;
#pragma unroll
  for (int j = 0; j < 16; ++j) {
    float m = (j < cnt) ? 1.0f : 0.0f;
    acc = fmaf(m, Z[(size_t)(e1[j] & (N_NODES - 1)) * KD + f], acc);
  }
  for (int t = 16; t < cnt; ++t)
    acc += Z[(size_t)elist[i * CAPE + t] * KD + f];
  return acc;
}

// Final stage B: out[i,f] = relu(DV[i]^-1/2 * sum of node i's edges)
template<int F>
__global__ __launch_bounds__(F) void node_gather(const float* __restrict__ Z,
                                                 const int* __restrict__ elist,
                                                 const int* __restrict__ DV,
                                                 float* __restrict__ out) {
  int i = blockIdx.x;
  int f = threadIdx.x;
  int cnt = DV[i]; if (cnt > CAPE) cnt = CAPE;
  float acc = node_acc<F>(Z, elist, i, f, cnt);
  out[(size_t)i * F + f] = fmaxf(acc * rsqrtf((float)DV[i]), 0.f);
}

// Fused stage B + GEMM: ROWS=8, 256 threads, 512 blocks (8 waves/CU).
template<int FO, bool WRITE_H>
__global__ __launch_bounds__(256) void node_gemm(const float* __restrict__ Z,
                                                 const int* __restrict__ elist,
                                                 const int* __restrict__ DV,
                                                 const float* __restrict__ W,
                                                 const float* __restrict__ bias,
                                                 float* __restrict__ P,
                                                 float* __restrict__ Hout) {
  constexpr int KD = 128;
  constexpr int ROWS = 8;
  constexpr int RPT = (FO == 128) ? 4 : 8;   // rows per thread
  __shared__ float ylds[ROWS * KD];
  int m0 = blockIdx.x * ROWS;
#pragma unroll
  for (int c0 = 0; c0 < ROWS * KD; c0 += 256) {
    int cell = c0 + threadIdx.x;
    int rr = cell >> 7, f = cell & 127;
    int i = m0 + rr;
    int cnt = DV[i]; if (cnt > CAPE) cnt = CAPE;
    float acc = node_acc<KD>(Z, elist, i, f, cnt);
    acc = fmaxf(acc * rsqrtf((float)DV[i]), 0.f);
    ylds[cell] = acc;
    if (WRITE_H) Hout[(size_t)i * KD + f] = acc;
  }
  __syncthreads();
  const int f  = (FO == 128) ? (threadIdx.x & 127) : threadIdx.x;
  const int rb = (FO == 128) ? ((threadIdx.x >> 7) * 4) : 0;
  float acc[RPT];
#pragma unroll
  for (int rr = 0; rr < RPT; ++rr) acc[rr] = 0.f;
  for (int k = 0; k < KD; k += 4) {
    float w0 = W[(size_t)(k + 0) * FO + f];
    float w1 = W[(size_t)(k + 1) * FO + f];
    float w2 = W[(size_t)(k + 2) * FO + f];
    float w3 = W[(size_t)(k + 3) * FO + f];
#pragma unroll
    for (int rr = 0; rr < RPT; ++rr) {
      float4 y = *reinterpret_cast<const float4*>(&ylds[(rb + rr) * KD + k]);
      acc[rr] = fmaf(y.x, w0, fmaf(y.y, w1, fmaf(y.z, w2, fmaf(y.w, w3, acc[rr]))));
    }
  }
  float bb = bias[f];
#pragma unroll
  for (int rr = 0; rr < RPT; ++rr)
    P[(size_t)(m0 + rb + rr) * FO + f] = acc[rr] + bb;
}

extern "C" void kernel_launch(void* const* d_in, const int* in_sizes, int n_in,
                              void* d_out, int out_size, void* d_ws, size_t ws_size,
                              hipStream_t stream) {
  const float* x   = (const float*)d_in[0];
  const float* adj = (const float*)d_in[1];
  const float* W10 = (const float*)d_in[2];
  const float* b10 = (const float*)d_in[3];
  const float* W11 = (const float*)d_in[4];
  const float* b11 = (const float*)d_in[5];
  const float* W20 = (const float*)d_in[6];
  const float* b20 = (const float*)d_in[7];
  const float* W21 = (const float*)d_in[8];
  const float* b21 = (const float*)d_in[9];
  float* out = (float*)d_out;

  char* w = (char*)d_ws;
  int*   idx   = (int*)(w + 0);            // 4096*9*4 = 147456
  int*   cur   = (int*)(w + 147456);       // 16384  (doubles as DV)
  int*   elist = (int*)(w + 163840);       // 524288 (uninitialized; clamped)
  float* bufP  = (float*)(w + 688128);     // 4 MB
  float* bufZ  = (float*)(w + 4882432);    // 4 MB

  float* x1out = out + (size_t)N_NODES * 256;
  float* x2out = x1out + (size_t)N_NODES * 128;

  // D1: [topk -> idx  ||  gemm_first (P1, x-copy, cur=0)] — independent halves
  s0_kernel<<<2 * GEMMB, 256, 0, stream>>>(x, adj, W10, b10, bufP, out, cur, idx);
  // D2: inverse edge list (cur becomes DV)
  build_elist<<<(N_NODES * KNN + 255) / 256, 256, 0, stream>>>(idx, cur, elist);

  // layer 1
  edge_gather<128><<<N_NODES, 128, 0, stream>>>(bufP, idx, cur, bufZ);
  node_gemm<128, false><<<N_NODES / 8, 256, 0, stream>>>(bufZ, elist, cur,
                                                         W11, b11, bufP, nullptr);
  edge_gather<128><<<N_NODES, 128, 0, stream>>>(bufP, idx, cur, bufZ);
  // x1 = relu(node gather); fused with layer-2 first GEMM, also writes x1out
  node_gemm<128, true><<<N_NODES / 8, 256, 0, stream>>>(bufZ, elist, cur,
                                                        W20, b20, bufP, x1out);
  // layer 2
  edge_gather<128><<<N_NODES, 128, 0, stream>>>(bufP, idx, cur, bufZ);
  node_gemm<256, false><<<N_NODES / 8, 256, 0, stream>>>(bufZ, elist, cur,
                                                         W21, b21, bufP, nullptr);
  edge_gather<256><<<N_NODES, 256, 0, stream>>>(bufP, idx, cur, bufZ);
  node_gather<256><<<N_NODES, 256, 0, stream>>>(bufZ, elist, cur, x2out);
}

// Round 17
// 89.595 us; speedup vs baseline: 1.0856x; 1.0856x over previous
//
#include <hip/hip_runtime.h>

#define N_NODES 4096
#define KNN 9
#define CAPS 128                // topk survivor capacity per row (2 per lane)
#define CAPE 32                 // max edges per node in strided elist
#define THRESH 0.99f
#define GEMMB 1024              // blocks in the topk half of s0

__device__ __forceinline__ bool vi_greater(float av, int aj, float bv, int bj) {
  // order: larger value first; ties -> smaller index first (matches lax.top_k)
  return (av > bv) || (av == bv && aj < bj);
}

// ---- S0: heterogeneous dispatch. Blocks [0,GEMMB): topk -> idx (long pole,
// launched first). Blocks [GEMMB,2*GEMMB): P1 = x W10 + b10, x->out copy,
// zero cur. Fully independent halves, no cross-group sync.
__global__ __launch_bounds__(256) void s0_kernel(const float* __restrict__ x,
                                                 const float* __restrict__ adj,
                                                 const float* __restrict__ W10,
                                                 const float* __restrict__ b10,
                                                 float* __restrict__ P,
                                                 float* __restrict__ xcopy,
                                                 int* __restrict__ cur,
                                                 int* __restrict__ idx) {
  __shared__ float sf[1024];          // topk: 4 wave regions x 128 ; gemm: ylds
  __shared__ int   si[512];           // topk: 4 wave regions x 128
  const int tid = threadIdx.x;

  if (blockIdx.x < GEMMB) {
    // ---------- topk half (R15-proven ballot-compaction scan) ----------
    const int lane = tid & 63, wv = tid >> 6;
    const int row = blockIdx.x * 4 + wv;
    const float4* r4 = reinterpret_cast<const float4*>(adj + (size_t)row * N_NODES);
    float* wval = sf + wv * CAPS;
    int*   widx = si + wv * CAPS;
    const unsigned long long lmask = (1ull << lane) - 1;

    // ballot-compaction of survivors > THRESH (diagonal filtered in rank phase)
    int n = 0;
#pragma unroll 4
    for (int t = 0; t < 16; ++t) {
      float4 f4 = r4[t * 64 + lane];
      float vals[4] = {f4.x, f4.y, f4.z, f4.w};
      int cb = (t * 64 + lane) * 4;
#pragma unroll
      for (int q = 0; q < 4; ++q) {
        bool pred = (vals[q] > THRESH);
        unsigned long long m = __ballot(pred);
        if (pred) {
          int p = n + __popcll(m & lmask);
          if (p < CAPS) { wval[p] = vals[q]; widx[p] = cb + q; }
        }
        n += __popcll(m);
      }
    }
    // per-wave LDS region written and read by the same wave: program order.

    if (n >= 9 && n <= CAPS) {
      // RANK-BASED top-8: candidate rank = #{valid survivors greater}.
      // Broadcast scan over LDS — parallel, no shfl chains. Ranks 0..7 are
      // the top-8; slot 8 = center node. idx bit-identical to extraction.
      bool val0 = lane < n, val1 = lane + 64 < n;
      float v0 = 0.f, v1 = 0.f; int c0 = -1, c1 = -1;
      if (val0) { v0 = wval[lane];      c0 = widx[lane]; }
      if (val1) { v1 = wval[lane + 64]; c1 = widx[lane + 64]; }
      if (c0 == row) val0 = false;      // reference zeroes the diagonal
      if (c1 == row) val1 = false;
      int r0 = 0, r1 = 0;
      if (n <= 64) {
        for (int s = 0; s < n; ++s) {
          float vs = wval[s]; int cs = widx[s];
          if (cs != row && vi_greater(vs, cs, v0, c0)) ++r0;
        }
      } else {
        for (int s = 0; s < n; ++s) {
          float vs = wval[s]; int cs = widx[s];
          bool d = (cs != row);
          if (d && vi_greater(vs, cs, v0, c0)) ++r0;
          if (d && vi_greater(vs, cs, v1, c1)) ++r1;
        }
      }
      if (val0 && r0 < 8) idx[row * KNN + r0] = c0;
      if (val1 && r1 < 8) idx[row * KNN + r1] = c1;
      if (lane == 0)      idx[row * KNN + 8] = row;
    } else {
      // exact fallback: full-row per-lane sorted top-9 + 9 extraction rounds
      const float* r = adj + (size_t)row * N_NODES;
      float v[9]; int ji[9];
#pragma unroll
      for (int t = 0; t < 9; ++t) { v[t] = -3.0e38f; ji[t] = 0x7fffffff; }
      for (int t = 0; t < 64; ++t) {
        int cc = t * 64 + lane;
        float val = (cc == row) ? 0.0f : r[cc];
        if (vi_greater(val, cc, v[8], ji[8])) {
          v[8] = val; ji[8] = cc;
#pragma unroll
          for (int s = 8; s > 0; --s) {
            if (vi_greater(v[s], ji[s], v[s-1], ji[s-1])) {
              float tv = v[s]; v[s] = v[s-1]; v[s-1] = tv;
              int tj = ji[s]; ji[s] = ji[s-1]; ji[s-1] = tj;
            }
          }
        }
      }
      int o0=0,o1=0,o2=0,o3=0,o4=0,o5=0,o6=0,o7=0,o8=0;
      bool has_center = false;
#pragma unroll
      for (int rnd = 0; rnd < 9; ++rnd) {
        float mv = v[0]; int mj = ji[0];
#pragma unroll
        for (int d = 1; d < 64; d <<= 1) {
          float ov = __shfl_xor(mv, d);
          int   oj = __shfl_xor(mj, d);
          if (vi_greater(ov, oj, mv, mj)) { mv = ov; mj = oj; }
        }
        switch (rnd) {   // static targets (avoid dynamic reg-array indexing)
          case 0: o0 = mj; break; case 1: o1 = mj; break;
          case 2: o2 = mj; break; case 3: o3 = mj; break;
          case 4: o4 = mj; break; case 5: o5 = mj; break;
          case 6: o6 = mj; break; case 7: o7 = mj; break;
          default: o8 = mj; break;
        }
        has_center = has_center || (mj == row);
        if (ji[0] == mj) {
#pragma unroll
          for (int s = 0; s < 8; ++s) { v[s] = v[s+1]; ji[s] = ji[s+1]; }
          v[8] = -3.0e38f; ji[8] = 0x7fffffff;
        }
      }
      if (!has_center) o8 = row;
      if (lane == 0) {
        int* ip = idx + row * KNN;
        ip[0]=o0; ip[1]=o1; ip[2]=o2; ip[3]=o3; ip[4]=o4;
        ip[5]=o5; ip[6]=o6; ip[7]=o7; ip[8]=o8;
      }
    }
  } else {
    // ---------- dense GEMM half ----------
    int bb0 = blockIdx.x - GEMMB;
    int gid = bb0 * 256 + tid;
    if (gid < N_NODES) cur[gid] = 0;
    int m0 = bb0 * 4;
    {
      float4 y4 = reinterpret_cast<const float4*>(x + (size_t)m0 * 256)[tid];
      reinterpret_cast<float4*>(sf)[tid] = y4;
      reinterpret_cast<float4*>(xcopy + (size_t)m0 * 256)[tid] = y4;
    }
    __syncthreads();
    const int f  = tid & 127;
    const int rb = (tid >> 7) * 2;
    float a0 = 0.f, a1 = 0.f;
    for (int k = 0; k < 256; k += 4) {
      float w0 = W10[(k + 0) * 128 + f];
      float w1 = W10[(k + 1) * 128 + f];
      float w2 = W10[(k + 2) * 128 + f];
      float w3 = W10[(k + 3) * 128 + f];
      float4 y0 = *reinterpret_cast<const float4*>(&sf[(rb + 0) * 256 + k]);
      float4 y1 = *reinterpret_cast<const float4*>(&sf[(rb + 1) * 256 + k]);
      a0 = fmaf(y0.x, w0, fmaf(y0.y, w1, fmaf(y0.z, w2, fmaf(y0.w, w3, a0))));
      a1 = fmaf(y1.x, w0, fmaf(y1.y, w1, fmaf(y1.z, w2, fmaf(y1.w, w3, a1))));
    }
    float bb = b10[f];
    P[(size_t)(m0 + rb + 0) * 128 + f] = a0 + bb;
    P[(size_t)(m0 + rb + 1) * 128 + f] = a1 + bb;
  }
}

// D2: build strided inverse list (cur zeroed in s0's gemm half; == DV after).
__global__ void build_elist(const int* __restrict__ idx, int* __restrict__ cur,
                            int* __restrict__ elist) {
  int t = blockIdx.x * blockDim.x + threadIdx.x;
  if (t >= N_NODES * KNN) return;
  int node = idx[t];
  int p = atomicAdd(&cur[node], 1);
  if (p < CAPE) elist[node * CAPE + p] = t / KNN;
}

// Stage A: Z[e,f] = (1/9) * sum_j DV[idx[e][j]]^-1/2 * Y[idx[e][j], f]
template<int F>
__global__ __launch_bounds__(F) void edge_gather(const float* __restrict__ Y,
                                                 const int* __restrict__ idx,
                                                 const int* __restrict__ DV,
                                                 float* __restrict__ Z) {
  __shared__ int er[KNN];
  __shared__ float ew[KNN];
  int e = blockIdx.x;
  if (threadIdx.x < KNN) {
    int r = idx[e * KNN + threadIdx.x];
    er[threadIdx.x] = r;
    ew[threadIdx.x] = rsqrtf((float)DV[r]);
  }
  __syncthreads();
  int f = threadIdx.x;
  float acc = 0.f;
#pragma unroll
  for (int j = 0; j < KNN; ++j)
    acc = fmaf(ew[j], Y[(size_t)er[j] * F + f], acc);
  Z[(size_t)e * F + f] = acc * (1.0f / 9.0f);
}

// Branch-free node accumulate: 16 unconditional masked loads. elist is NOT
// initialized — entries clamped in-bounds with &(N-1); cndmask zeroes poison.
template<int KD>
__device__ __forceinline__ float node_acc(const float* __restrict__ Z,
                                          const int* __restrict__ elist,
                                          int i, int f, int cnt) {
  const int4* el4 = reinterpret_cast<const int4*>(elist + i * CAPE);
  int4 ea = el4[0], eb = el4[1], ec = el4[2], ed = el4[3];
  int e1[16] = {ea.x, ea.y, ea.z, ea.w, eb.x, eb.y, eb.z, eb.w,
                ec.x, ec.y, ec.z, ec.w, ed.x, ed.y, ed.z, ed.w};
  float acc = 0.f;
#pragma unroll
  for (int j = 0; j < 16; ++j) {
    float m = (j < cnt) ? 1.0f : 0.0f;
    acc = fmaf(m, Z[(size_t)(e1[j] & (N_NODES - 1)) * KD + f], acc);
  }
  for (int t = 16; t < cnt; ++t)
    acc += Z[(size_t)elist[i * CAPE + t] * KD + f];
  return acc;
}

// Final stage B: out[i,f] = relu(DV[i]^-1/2 * sum of node i's edges)
template<int F>
__global__ __launch_bounds__(F) void node_gather(const float* __restrict__ Z,
                                                 const int* __restrict__ elist,
                                                 const int* __restrict__ DV,
                                                 float* __restrict__ out) {
  int i = blockIdx.x;
  int f = threadIdx.x;
  int cnt = DV[i]; if (cnt > CAPE) cnt = CAPE;
  float acc = node_acc<F>(Z, elist, i, f, cnt);
  out[(size_t)i * F + f] = fmaxf(acc * rsqrtf((float)DV[i]), 0.f);
}

// Fused stage B + GEMM: ROWS=4, 256 threads, 1024 blocks -> 16 waves/CU
// (4/SIMD) to hide the gather's scattered-L2 latency. GEMM: FO=128:
// thread-half owns 2 rows; FO=256: thread owns all 4.
template<int FO, bool WRITE_H>
__global__ __launch_bounds__(256) void node_gemm(const float* __restrict__ Z,
                                                 const int* __restrict__ elist,
                                                 const int* __restrict__ DV,
                                                 const float* __restrict__ W,
                                                 const float* __restrict__ bias,
                                                 float* __restrict__ P,
                                                 float* __restrict__ Hout) {
  constexpr int KD = 128;
  constexpr int ROWS = 4;
  constexpr int RPT = (FO == 128) ? 2 : 4;   // rows per thread
  __shared__ float ylds[ROWS * KD];
  int m0 = blockIdx.x * ROWS;
#pragma unroll
  for (int c0 = 0; c0 < ROWS * KD; c0 += 256) {
    int cell = c0 + threadIdx.x;
    int rr = cell >> 7, f = cell & 127;
    int i = m0 + rr;
    int cnt = DV[i]; if (cnt > CAPE) cnt = CAPE;
    float acc = node_acc<KD>(Z, elist, i, f, cnt);
    acc = fmaxf(acc * rsqrtf((float)DV[i]), 0.f);
    ylds[cell] = acc;
    if (WRITE_H) Hout[(size_t)i * KD + f] = acc;
  }
  __syncthreads();
  const int f  = (FO == 128) ? (threadIdx.x & 127) : threadIdx.x;
  const int rb = (FO == 128) ? ((threadIdx.x >> 7) * 2) : 0;
  float acc[RPT];
#pragma unroll
  for (int rr = 0; rr < RPT; ++rr) acc[rr] = 0.f;
  for (int k = 0; k < KD; k += 4) {
    float w0 = W[(size_t)(k + 0) * FO + f];
    float w1 = W[(size_t)(k + 1) * FO + f];
    float w2 = W[(size_t)(k + 2) * FO + f];
    float w3 = W[(size_t)(k + 3) * FO + f];
#pragma unroll
    for (int rr = 0; rr < RPT; ++rr) {
      float4 y = *reinterpret_cast<const float4*>(&ylds[(rb + rr) * KD + k]);
      acc[rr] = fmaf(y.x, w0, fmaf(y.y, w1, fmaf(y.z, w2, fmaf(y.w, w3, acc[rr]))));
    }
  }
  float bb = bias[f];
#pragma unroll
  for (int rr = 0; rr < RPT; ++rr)
    P[(size_t)(m0 + rb + rr) * FO + f] = acc[rr] + bb;
}

extern "C" void kernel_launch(void* const* d_in, const int* in_sizes, int n_in,
                              void* d_out, int out_size, void* d_ws, size_t ws_size,
                              hipStream_t stream) {
  const float* x   = (const float*)d_in[0];
  const float* adj = (const float*)d_in[1];
  const float* W10 = (const float*)d_in[2];
  const float* b10 = (const float*)d_in[3];
  const float* W11 = (const float*)d_in[4];
  const float* b11 = (const float*)d_in[5];
  const float* W20 = (const float*)d_in[6];
  const float* b20 = (const float*)d_in[7];
  const float* W21 = (const float*)d_in[8];
  const float* b21 = (const float*)d_in[9];
  float* out = (float*)d_out;

  char* w = (char*)d_ws;
  int*   idx   = (int*)(w + 0);            // 4096*9*4 = 147456
  int*   cur   = (int*)(w + 147456);       // 16384  (doubles as DV)
  int*   elist = (int*)(w + 163840);       // 524288 (uninitialized; clamped)
  float* bufP  = (float*)(w + 688128);     // 4 MB
  float* bufZ  = (float*)(w + 4882432);    // 4 MB

  float* x1out = out + (size_t)N_NODES * 256;
  float* x2out = x1out + (size_t)N_NODES * 128;

  // D1: [topk -> idx  ||  gemm_first (P1, x-copy, cur=0)] — independent halves
  s0_kernel<<<2 * GEMMB, 256, 0, stream>>>(x, adj, W10, b10, bufP, out, cur, idx);
  // D2: inverse edge list (cur becomes DV)
  build_elist<<<(N_NODES * KNN + 255) / 256, 256, 0, stream>>>(idx, cur, elist);

  // layer 1
  edge_gather<128><<<N_NODES, 128, 0, stream>>>(bufP, idx, cur, bufZ);
  node_gemm<128, false><<<N_NODES / 4, 256, 0, stream>>>(bufZ, elist, cur,
                                                         W11, b11, bufP, nullptr);
  edge_gather<128><<<N_NODES, 128, 0, stream>>>(bufP, idx, cur, bufZ);
  // x1 = relu(node gather); fused with layer-2 first GEMM, also writes x1out
  node_gemm<128, true><<<N_NODES / 4, 256, 0, stream>>>(bufZ, elist, cur,
                                                        W20, b20, bufP, x1out);
  // layer 2
  edge_gather<128><<<N_NODES, 128, 0, stream>>>(bufP, idx, cur, bufZ);
  node_gemm<256, false><<<N_NODES / 4, 256, 0, stream>>>(bufZ, elist, cur,
                                                         W21, b21, bufP, nullptr);
  edge_gather<256><<<N_NODES, 256, 0, stream>>>(bufP, idx, cur, bufZ);
  node_gather<256><<<N_NODES, 256, 0, stream>>>(bufZ, elist, cur, x2out);
}